// Round 5
// baseline (816.004 us; speedup 1.0000x reference)
//
#include <hip/hip_runtime.h>
#include <hip/hip_bf16.h>
#include <stdint.h>

typedef unsigned short ushortT;
typedef __bf16 bf16x8 __attribute__((ext_vector_type(8)));
typedef float f32x4 __attribute__((ext_vector_type(4)));
typedef unsigned short u16x8 __attribute__((ext_vector_type(8)));

#define N_TOK 131072
#define NSEG  256

__device__ __forceinline__ uint32_t f2bf(float f) {
  union { float f; uint32_t u; } c; c.f = f;
  uint32_t u = c.u;
  u += 0x7fffu + ((u >> 16) & 1u);   // RNE
  return u >> 16;
}
__device__ __forceinline__ float bf2f(uint32_t b) {
  union { uint32_t u; float f; } c; c.u = b << 16;
  return c.f;
}

// ---------------- prep kernels ----------------

// Pack W [Kd][Nd] row-major f32 -> Wpk bf16 with layout
// idx = cb*(Kd*64) + kk*2048 + q*512 + ct*128 + lr*8 + e
// where col = cb*64 + ct*16 + lr, k = kk*32 + q*8 + e.
// Per-wave MFMA B-operand then needs ONE base pointer + imm offsets.
__global__ void pack_w_kernel(const float* __restrict__ W, ushortT* __restrict__ Wpk,
                              int Kd, int Nd) {
  int i = blockIdx.x * 256 + threadIdx.x;
  if (i >= Kd * Nd) return;
  const int e   = i & 7;
  const int lr  = (i >> 3) & 15;
  const int ct  = (i >> 7) & 3;
  const int q   = (i >> 9) & 3;
  const int rest = i >> 11;
  const int kkn = Kd >> 5;
  const int kk  = rest % kkn;
  const int cb  = rest / kkn;
  const int n = cb * 64 + ct * 16 + lr;
  const int k = kk * 32 + q * 8 + e;
  Wpk[i] = (ushortT)f2bf(W[(size_t)k * Nd + n]);
}

// weff[c*8+h] = sum_d Wk[c,h*128+d]*Wq[h,d] / sqrt(128),  c in [0,640)
__global__ void weff_kernel(const float* __restrict__ Wk, const float* __restrict__ Wq,
                            float* __restrict__ weff) {
  const int c = blockIdx.x;       // 640
  const int lane = threadIdx.x;   // 64
  const float rs = 0.08838834764831845f;
#pragma unroll
  for (int h = 0; h < 8; ++h) {
    float acc = Wk[(size_t)c * 1024 + h * 128 + lane] * Wq[h * 128 + lane]
              + Wk[(size_t)c * 1024 + h * 128 + 64 + lane] * Wq[h * 128 + 64 + lane];
#pragma unroll
    for (int off = 32; off >= 1; off >>= 1) acc += __shfl_xor(acc, off, 64);
    if (lane == 0) weff[c * 8 + h] = acc * rs;
  }
}

// ---------------- fused MLP chain ----------------
// One block = 64 token rows. LDS h [64 rows][1024 B] bf16, swizzled:
//   byte(row, col) = row*1024 + ((col*2) ^ ((row&7)<<4))
// 8 waves; wave wv owns output cols [wv*64, wv*64+64). acc[4][4] per wave.
// Each layer: MFMA phase (A from LDS, B from packed global) -> barrier ->
// epilogue writes h in place (swizzled) -> barrier. Final layer output is
// copied LDS->global coalesced (dwordx4).

template <int K, bool RELU, bool BIAS>
__device__ __forceinline__ void layer_fn(char* hb, const ushortT* __restrict__ Wpk,
                                         const float* __restrict__ bias,
                                         int wv, int lane) {
  constexpr int KS = K / 32;
  const int q  = lane >> 4;
  const int lr = lane & 15;
  const int xk = lane & 7;          // row&7 for A-frag rows (rt*16 + lr)
  char* hlane = hb + lr * 1024;     // + imm rt*16384 + dynamic chunk

  f32x4 acc[4][4];
#pragma unroll
  for (int i = 0; i < 4; ++i)
#pragma unroll
    for (int j = 0; j < 4; ++j) acc[i][j] = 0.f;

  const ushortT* p = Wpk + (size_t)wv * (K * 64) + q * 512 + lr * 8;

  bf16x8 bcur[4], bnxt[4];
#pragma unroll
  for (int ct = 0; ct < 4; ++ct) bcur[ct] = *(const bf16x8*)(p + ct * 128);

#pragma unroll
  for (int kk = 0; kk < KS; ++kk) {
    p += 2048;
    if (kk + 1 < KS) {
#pragma unroll
      for (int ct = 0; ct < 4; ++ct) bnxt[ct] = *(const bf16x8*)(p + ct * 128);
    }
    bf16x8 a[4];
    const int chunk = ((kk * 4 + q) ^ xk) << 4;
#pragma unroll
    for (int rt = 0; rt < 4; ++rt)
      a[rt] = *(const bf16x8*)(hlane + rt * 16384 + chunk);
#pragma unroll
    for (int ct = 0; ct < 4; ++ct)
#pragma unroll
      for (int rt = 0; rt < 4; ++rt)
        acc[rt][ct] = __builtin_amdgcn_mfma_f32_16x16x32_bf16(a[rt], bcur[ct], acc[rt][ct], 0, 0, 0);
#pragma unroll
    for (int ct = 0; ct < 4; ++ct) bcur[ct] = bnxt[ct];
  }

  __syncthreads();   // all reads of h complete before overwrite

  // C/D layout: col = colbase + (lane&15), row = rt*16 + q*4 + r
#pragma unroll
  for (int ct = 0; ct < 4; ++ct) {
    const int col2 = (wv * 64 + ct * 16 + lr) * 2;
    const float bvv = BIAS ? bias[wv * 64 + ct * 16 + lr] : 0.f;
#pragma unroll
    for (int rt = 0; rt < 4; ++rt) {
#pragma unroll
      for (int r = 0; r < 4; ++r) {
        const int row = rt * 16 + q * 4 + r;
        float v = acc[rt][ct][r] + bvv;
        if (RELU) v = fmaxf(v, 0.f);
        *(ushortT*)(hb + row * 1024 + (col2 ^ ((row & 7) << 4))) = (ushortT)f2bf(v);
      }
    }
  }
  __syncthreads();
}

__global__ __launch_bounds__(512, 4)
void fused_chain_kernel(const float* __restrict__ X,
                        const ushortT* __restrict__ W1p, const float* __restrict__ b1,
                        const ushortT* __restrict__ W2p, const float* __restrict__ b2,
                        const ushortT* __restrict__ W3p, const float* __restrict__ b3,
                        const ushortT* __restrict__ Wrp, ushortT* __restrict__ Z) {
  __shared__ char hbuf[64 * 1024];   // [64 rows][512 cols] bf16, swizzled

  const int t = (int)threadIdx.x;
  const int wv = t >> 6, lane = t & 63;
  const int blk = (int)blockIdx.x;

  // ---- stage X (64 rows x 128 cols f32 -> bf16, swizzled) ----
  {
    const float4* Xs = (const float4*)(X + (size_t)blk * 64 * 128);
    const int row = t >> 3, sub = t & 7;
    char* rowp = hbuf + row * 1024;
    const int xr = (row & 7) << 4;
#pragma unroll
    for (int j = 0; j < 4; ++j) {
      const float4 v = Xs[row * 32 + sub * 4 + j];
      uint2 pk;
      pk.x = f2bf(v.x) | (f2bf(v.y) << 16);
      pk.y = f2bf(v.z) | (f2bf(v.w) << 16);
      *(uint2*)(rowp + (((sub * 4 + j) * 8) ^ xr)) = pk;
    }
  }
  __syncthreads();

  layer_fn<128, true,  true >(hbuf, W1p, b1, wv, lane);
  layer_fn<512, true,  true >(hbuf, W2p, b2, wv, lane);
  layer_fn<512, true,  true >(hbuf, W3p, b3, wv, lane);
  layer_fn<512, false, false>(hbuf, Wrp, nullptr, wv, lane);

  // ---- coalesced copy-out: LDS (swizzled) -> Z, 16B per thread per iter ----
  {
    uint4* Zb = (uint4*)(Z + (size_t)blk * 64 * 512);   // 64 uint4 per row
    const int row = t >> 3, sub = t & 7;
    const char* rowp = hbuf + row * 1024;
    const int xr = (row & 7) << 4;
#pragma unroll
    for (int j = 0; j < 8; ++j) {
      const int chunk = j * 8 + sub;
      Zb[row * 64 + chunk] = *(const uint4*)(rowp + ((chunk * 16) ^ xr));
    }
  }
}

// ---------------- segment prefix-mean scan with cross-chunk carry ----------------

__global__ __launch_bounds__(256)
void scan_kernel(const ushortT* __restrict__ z, ushortT* __restrict__ gout,
                 const int* __restrict__ seg, const float* __restrict__ br,
                 float* __restrict__ carry_sum, int* __restrict__ carry_cnt,
                 int c0, int rows) {
  const int s = (int)blockIdx.x;   // segment id
  const int t = (int)threadIdx.x;  // word (2 cols) owner

  int lo = c0, hi = c0 + rows;
  while (lo < hi) { int m = (lo + hi) >> 1; if (seg[m] < s) lo = m + 1; else hi = m; }
  const int beg = lo;
  hi = c0 + rows;
  while (lo < hi) { int m = (lo + hi) >> 1; if (seg[m] < s + 1) lo = m + 1; else hi = m; }
  const int end = lo;
  if (end <= beg) return;

  const float b0 = br[2 * t], b1v = br[2 * t + 1];
  float a0 = carry_sum[s * 512 + 2 * t];
  float a1 = carry_sum[s * 512 + 2 * t + 1];
  const int cntBase = carry_cnt[s];
  const uint32_t* __restrict__ zp = (const uint32_t*)z;
  uint32_t* __restrict__ gp = (uint32_t*)gout;

  constexpr int P = 16;
  uint32_t buf[P];
#pragma unroll
  for (int p = 0; p < P; ++p)
    buf[p] = (beg + p < end) ? zp[(size_t)(beg + p - c0) * 256 + t] : 0u;

  int base = beg;
  for (; base + 2 * P <= end; base += P) {
#pragma unroll
    for (int p = 0; p < P; ++p) {
      const int r = base + p;
      const uint32_t v = buf[p];
      buf[p] = zp[(size_t)(r + P - c0) * 256 + t];
      a0 += bf2f(v & 0xffffu);
      a1 += bf2f(v >> 16);
      const float inv = 1.0f / (float)(cntBase + r - beg + 1);
      const float g0 = fmaxf(fmaf(a0, inv, b0), 0.f);
      const float g1 = fmaxf(fmaf(a1, inv, b1v), 0.f);
      gp[(size_t)(r - c0) * 256 + t] = f2bf(g0) | (f2bf(g1) << 16);
    }
  }
  for (; base < end; base += P) {
#pragma unroll
    for (int p = 0; p < P; ++p) {
      const int r = base + p;
      if (r < end) {
        const uint32_t v = buf[p];
        buf[p] = (r + P < end) ? zp[(size_t)(r + P - c0) * 256 + t] : 0u;
        a0 += bf2f(v & 0xffffu);
        a1 += bf2f(v >> 16);
        const float inv = 1.0f / (float)(cntBase + r - beg + 1);
        const float g0 = fmaxf(fmaf(a0, inv, b0), 0.f);
        const float g1 = fmaxf(fmaf(a1, inv, b1v), 0.f);
        gp[(size_t)(r - c0) * 256 + t] = f2bf(g0) | (f2bf(g1) << 16);
      }
    }
  }

  carry_sum[s * 512 + 2 * t]     = a0;
  carry_sum[s * 512 + 2 * t + 1] = a1;
  if (t == 0) carry_cnt[s] = cntBase + (end - beg);
}

// ---------------- final: out[n,h] = X[n,:]@weff[0:128,h] + g[n,:]@weff[128:640,h] ----------------

__global__ __launch_bounds__(256)
void final_kernel(const float* __restrict__ X, const ushortT* __restrict__ g,
                  const float* __restrict__ weff, float* __restrict__ out, int rows) {
  const int t = (int)threadIdx.x;
  const int wv = t >> 6, lane = t & 63;

  float wx0[8], wx1[8], wg[8][8];
#pragma unroll
  for (int h = 0; h < 8; ++h) {
    wx0[h] = weff[(2 * lane) * 8 + h];
    wx1[h] = weff[(2 * lane + 1) * 8 + h];
  }
#pragma unroll
  for (int j = 0; j < 8; ++j)
#pragma unroll
    for (int h = 0; h < 8; ++h)
      wg[j][h] = weff[(128 + 8 * lane + j) * 8 + h];

  for (int row = (int)blockIdx.x * 4 + wv; row < rows; row += (int)gridDim.x * 4) {
    const float2 xv = *(const float2*)&X[(size_t)row * 128 + 2 * lane];
    const u16x8 gv = *(const u16x8*)&g[(size_t)row * 512 + 8 * lane];
    float pp[8];
#pragma unroll
    for (int h = 0; h < 8; ++h) pp[h] = xv.x * wx0[h] + xv.y * wx1[h];
#pragma unroll
    for (int j = 0; j < 8; ++j) {
      const float f = bf2f((uint32_t)gv[j]);
#pragma unroll
      for (int h = 0; h < 8; ++h) pp[h] = fmaf(f, wg[j][h], pp[h]);
    }
#pragma unroll
    for (int off = 32; off >= 1; off >>= 1) {
#pragma unroll
      for (int h = 0; h < 8; ++h) pp[h] += __shfl_xor(pp[h], off, 64);
    }
    if (lane == 0) {
#pragma unroll
      for (int h = 0; h < 8; ++h) out[(size_t)row * 8 + h] = pp[h];
    }
  }
}

// ---------------- launch ----------------

extern "C" void kernel_launch(void* const* d_in, const int* in_sizes, int n_in,
                              void* d_out, int out_size, void* d_ws, size_t ws_size,
                              hipStream_t stream) {
  const float* X  = (const float*)d_in[0];
  const int*   sg = (const int*)d_in[1];
  const float* W1 = (const float*)d_in[2];
  const float* b1 = (const float*)d_in[3];
  const float* W2 = (const float*)d_in[4];
  const float* b2 = (const float*)d_in[5];
  const float* W3 = (const float*)d_in[6];
  const float* b3 = (const float*)d_in[7];
  const float* Wr = (const float*)d_in[8];
  const float* br = (const float*)d_in[9];
  const float* Wk = (const float*)d_in[10];
  const float* Wq = (const float*)d_in[11];
  float* out = (float*)d_out;

  const size_t szW1  = 512 * 128 * 2;
  const size_t szW   = 512 * 512 * 2;
  const size_t szWeff = 640 * 8 * 4;
  const size_t szCSum = NSEG * 512 * 4;
  const size_t szCCnt = NSEG * 4;
  const size_t fixed  = szW1 + 3 * szW + szWeff + szCSum + szCCnt;

  int CH = 0;
  const int cands[6] = {131072, 65536, 32768, 16384, 8192, 4096};
  for (int i = 0; i < 6; ++i) {
    const size_t need = fixed + 2 * (size_t)cands[i] * 512 * 2;  // z + g ping-pong
    if (need <= ws_size) { CH = cands[i]; break; }
  }
  if (CH == 0) CH = 4096;

  char* p = (char*)d_ws;
  ushortT* W1p  = (ushortT*)p; p += szW1;
  ushortT* W2p  = (ushortT*)p; p += szW;
  ushortT* W3p  = (ushortT*)p; p += szW;
  ushortT* Wrp  = (ushortT*)p; p += szW;
  float*   weff = (float*)p;   p += szWeff;
  float*   cSum = (float*)p;   p += szCSum;
  int*     cCnt = (int*)p;     p += szCCnt;
  ushortT* p1   = (ushortT*)p; p += (size_t)CH * 512 * 2;
  ushortT* p2   = (ushortT*)p;

  pack_w_kernel<<<(512 * 128) / 256, 256, 0, stream>>>(W1, W1p, 128, 512);
  pack_w_kernel<<<(512 * 512) / 256, 256, 0, stream>>>(W2, W2p, 512, 512);
  pack_w_kernel<<<(512 * 512) / 256, 256, 0, stream>>>(W3, W3p, 512, 512);
  pack_w_kernel<<<(512 * 512) / 256, 256, 0, stream>>>(Wr, Wrp, 512, 512);
  weff_kernel<<<640, 64, 0, stream>>>(Wk, Wq, weff);
  hipMemsetAsync(cSum, 0, szCSum + szCCnt, stream);

  for (int c0 = 0; c0 < N_TOK; c0 += CH) {
    const int gF = (CH / 4 < 4096) ? CH / 4 : 4096;
    fused_chain_kernel<<<CH / 64, 512, 0, stream>>>(X + (size_t)c0 * 128,
                                                    W1p, b1, W2p, b2, W3p, b3, Wrp, p2);
    scan_kernel<<<NSEG, 256, 0, stream>>>(p2, p1, sg, br, cSum, cCnt, c0, CH);
    final_kernel<<<gF, 256, 0, stream>>>(X + (size_t)c0 * 128, p1, weff,
                                         out + (size_t)c0 * 8, CH);
  }
}

// Round 6
// 575.832 us; speedup vs baseline: 1.4171x; 1.4171x over previous
//
#include <hip/hip_runtime.h>
#include <hip/hip_bf16.h>
#include <stdint.h>

typedef unsigned short ushortT;
typedef __bf16 bf16x8 __attribute__((ext_vector_type(8)));
typedef float f32x4 __attribute__((ext_vector_type(4)));
typedef unsigned short u16x8 __attribute__((ext_vector_type(8)));

#define N_TOK 131072
#define NSEG  256

__device__ __forceinline__ uint32_t f2bf(float f) {
  union { float f; uint32_t u; } c; c.f = f;
  uint32_t u = c.u;
  u += 0x7fffu + ((u >> 16) & 1u);   // RNE
  return u >> 16;
}
__device__ __forceinline__ float bf2f(uint32_t b) {
  union { uint32_t u; float f; } c; c.u = b << 16;
  return c.f;
}

__device__ __forceinline__ void gload_lds16(const void* g, void* l) {
  __builtin_amdgcn_global_load_lds(
      (const __attribute__((address_space(1))) void*)g,
      (__attribute__((address_space(3))) void*)l, 16, 0, 0);
}

// ---------------- prep kernels ----------------

__global__ void convert_bf16_kernel(const float* __restrict__ X, ushortT* __restrict__ Xb, int n4) {
  int i = blockIdx.x * 256 + threadIdx.x;
  const int stride = gridDim.x * 256;
  for (int idx = i; idx < n4; idx += stride) {
    const float4 v = ((const float4*)X)[idx];
    uint2 pk;
    pk.x = f2bf(v.x) | (f2bf(v.y) << 16);
    pk.y = f2bf(v.z) | (f2bf(v.w) << 16);
    ((uint2*)Xb)[idx] = pk;
  }
}

// WT[n*Kd + k] = bf16(W[k*Nd + n]);  W is [Kd][Nd] row-major
__global__ void transpose_bf16_kernel(const float* __restrict__ W, ushortT* __restrict__ WT,
                                      int Kd, int Nd) {
  int i = blockIdx.x * 256 + threadIdx.x;
  if (i < Kd * Nd) {
    int n = i / Kd, k = i % Kd;
    WT[i] = (ushortT)f2bf(W[(size_t)k * Nd + n]);
  }
}

// weff[c*8+h] = sum_d Wk[c,h*128+d]*Wq[h,d] / sqrt(128),  c in [0,640)
__global__ void weff_kernel(const float* __restrict__ Wk, const float* __restrict__ Wq,
                            float* __restrict__ weff) {
  const int c = blockIdx.x;       // 640
  const int lane = threadIdx.x;   // 64
  const float rs = 0.08838834764831845f;
#pragma unroll
  for (int h = 0; h < 8; ++h) {
    float acc = Wk[(size_t)c * 1024 + h * 128 + lane] * Wq[h * 128 + lane]
              + Wk[(size_t)c * 1024 + h * 128 + 64 + lane] * Wq[h * 128 + 64 + lane];
#pragma unroll
    for (int off = 32; off >= 1; off >>= 1) acc += __shfl_xor(acc, off, 64);
    if (lane == 0) weff[c * 8 + h] = acc * rs;
  }
}

// ---------------- ring GEMM: C[M,512] = relu?(A[M,K] @ W + bias) ----------------
// Tile 256x128, BK=64, 8 waves (4M x 2N), wave output 64x64 (acc[4][4]).
// LDS: 3-slot ring, slot = A[256][64] (32KB, XOR-swizzled) + B[128][64] (16KB).
// Schedule: iter j stages tile j+2 (6 gload_lds/thread), computes tile j,
// then s_waitcnt vmcnt(6) + raw s_barrier (tile j+1 landed, j+2 in flight).
// Swizzle: 16B chunk c of row r stored at chunk (c ^ (r&7)); applied on the
// GLOBAL source during staging and on the ds_read address (same involution).

template <int K, bool RELU, bool BIAS>
__global__ __launch_bounds__(512, 2)
void gemm_ring_kernel(const ushortT* __restrict__ A, const ushortT* __restrict__ BT,
                      const float* __restrict__ bias, ushortT* __restrict__ C) {
  __shared__ char lds[3 * 49152];
  constexpr int NT = K / 64;

  // XCD-aware swizzle (nwg multiple of 8)
  const int nwg  = (int)gridDim.x;
  const int cpx  = nwg >> 3;
  const int flat = (int)blockIdx.x;
  const int swz  = (flat & 7) * cpx + (flat >> 3);
  const int bm   = swz >> 2;   // 256-row blocks
  const int bn   = swz & 3;    // 4 col blocks of 128

  const int t = (int)threadIdx.x;
  const int w = t >> 6, lane = t & 63;
  const int wm = w >> 1, wn = w & 1;
  const int q = lane >> 4, lr = lane & 15;

  // staging: pass p covers tile-rows [p*64, p*64+64); thread t -> row p*64+(t>>3),
  // stores chunk (t&7); global source chunk = (t&7) ^ (row&7)
  const int srow   = t >> 3;
  const int schunk = (t & 7) ^ (srow & 7);
  const ushortT* Ag = A  + (size_t)(bm * 256 + srow) * K + schunk * 8;
  const ushortT* Bg = BT + (size_t)(bn * 128 + srow) * K + schunk * 8;

  f32x4 acc[4][4];
#pragma unroll
  for (int i = 0; i < 4; ++i)
#pragma unroll
    for (int j = 0; j < 4; ++j) acc[i][j] = 0.f;

  const int arow0 = wm * 64 + lr;           // + m*16
  const int brow0 = wn * 64 + lr;           // + n*16
  const int c0 = (q ^ (lr & 7)) << 4;       // kk=0 chunk byte offset
  const int c1 = c0 ^ 64;                   // kk=1: (4+q)^(lr&7) = c0^4 chunks

#define STAGE_TILE(tile)                                                        \
  {                                                                             \
    const int _sl = (tile) % 3;                                                 \
    char* _la = lds + _sl * 49152 + t * 16;                                     \
    const ushortT* _ga = Ag + (tile) * 64;                                      \
    _Pragma("unroll")                                                           \
    for (int _p = 0; _p < 4; ++_p)                                              \
      gload_lds16(_ga + (size_t)_p * 64 * K, _la + _p * 8192);                  \
    char* _lb = lds + _sl * 49152 + 32768 + t * 16;                             \
    const ushortT* _gb = Bg + (tile) * 64;                                      \
    _Pragma("unroll")                                                           \
    for (int _p = 0; _p < 2; ++_p)                                              \
      gload_lds16(_gb + (size_t)_p * 64 * K, _lb + _p * 8192);                  \
  }

  // prologue: tiles 0,1 in flight; wait tile 0 (6 loads of tile 1 outstanding)
  STAGE_TILE(0);
  if (NT > 1) STAGE_TILE(1);
  asm volatile("s_waitcnt vmcnt(6)" ::: "memory");
  __builtin_amdgcn_s_barrier();
  asm volatile("" ::: "memory");

  int sl = 0;
#pragma unroll 1
  for (int j = 0; j < NT; ++j) {
    if (j + 2 < NT) STAGE_TILE(j + 2);

    const char* sa = lds + sl * 49152;
    const char* sb = sa + 32768;
    bf16x8 a0[4], a1[4], b0v[4], b1v[4];
#pragma unroll
    for (int m = 0; m < 4; ++m) {
      const int ro = (arow0 + m * 16) * 128;
      a0[m] = *(const bf16x8*)(sa + ro + c0);
      a1[m] = *(const bf16x8*)(sa + ro + c1);
    }
#pragma unroll
    for (int n = 0; n < 4; ++n) {
      const int ro = (brow0 + n * 16) * 128;
      b0v[n] = *(const bf16x8*)(sb + ro + c0);
      b1v[n] = *(const bf16x8*)(sb + ro + c1);
    }

    __builtin_amdgcn_s_setprio(1);
#pragma unroll
    for (int n = 0; n < 4; ++n)
#pragma unroll
      for (int m = 0; m < 4; ++m)
        acc[m][n] = __builtin_amdgcn_mfma_f32_16x16x32_bf16(a0[m], b0v[n], acc[m][n], 0, 0, 0);
#pragma unroll
    for (int n = 0; n < 4; ++n)
#pragma unroll
      for (int m = 0; m < 4; ++m)
        acc[m][n] = __builtin_amdgcn_mfma_f32_16x16x32_bf16(a1[m], b1v[n], acc[m][n], 0, 0, 0);
    __builtin_amdgcn_s_setprio(0);

    if (j + 2 < NT) {
      asm volatile("s_waitcnt vmcnt(6)" ::: "memory");
      __builtin_amdgcn_s_barrier();
      asm volatile("" ::: "memory");
    } else if (j + 1 < NT) {
      asm volatile("s_waitcnt vmcnt(0)" ::: "memory");
      __builtin_amdgcn_s_barrier();
      asm volatile("" ::: "memory");
    }
    sl = (sl == 2) ? 0 : sl + 1;
  }
#undef STAGE_TILE

  // C/D layout (validated R3): col = base + (lane&15), row = base + q*4 + r
  const int row0 = bm * 256 + wm * 64 + q * 4;
  const int col0 = bn * 128 + wn * 64 + lr;
#pragma unroll
  for (int n = 0; n < 4; ++n) {
    const int col = col0 + n * 16;
    const float bvv = BIAS ? bias[col] : 0.f;
#pragma unroll
    for (int m = 0; m < 4; ++m) {
#pragma unroll
      for (int r = 0; r < 4; ++r) {
        float v = acc[m][n][r] + bvv;
        if (RELU) v = fmaxf(v, 0.f);
        C[(size_t)(row0 + m * 16 + r) * 512 + col] = (ushortT)f2bf(v);
      }
    }
  }
}

// ---------------- segment prefix-mean scan with cross-chunk carry ----------------

__global__ __launch_bounds__(256)
void scan_kernel(const ushortT* __restrict__ z, ushortT* __restrict__ gout,
                 const int* __restrict__ seg, const float* __restrict__ br,
                 float* __restrict__ carry_sum, int* __restrict__ carry_cnt,
                 int c0, int rows) {
  const int s = (int)blockIdx.x;   // segment id
  const int t = (int)threadIdx.x;  // word (2 cols) owner

  int lo = c0, hi = c0 + rows;
  while (lo < hi) { int m = (lo + hi) >> 1; if (seg[m] < s) lo = m + 1; else hi = m; }
  const int beg = lo;
  hi = c0 + rows;
  while (lo < hi) { int m = (lo + hi) >> 1; if (seg[m] < s + 1) lo = m + 1; else hi = m; }
  const int end = lo;
  if (end <= beg) return;

  const float b0 = br[2 * t], b1v = br[2 * t + 1];
  float a0 = carry_sum[s * 512 + 2 * t];
  float a1 = carry_sum[s * 512 + 2 * t + 1];
  const int cntBase = carry_cnt[s];
  const uint32_t* __restrict__ zp = (const uint32_t*)z;
  uint32_t* __restrict__ gp = (uint32_t*)gout;

  constexpr int P = 16;
  uint32_t buf[P];
#pragma unroll
  for (int p = 0; p < P; ++p)
    buf[p] = (beg + p < end) ? zp[(size_t)(beg + p - c0) * 256 + t] : 0u;

  int base = beg;
  for (; base + 2 * P <= end; base += P) {
#pragma unroll
    for (int p = 0; p < P; ++p) {
      const int r = base + p;
      const uint32_t v = buf[p];
      buf[p] = zp[(size_t)(r + P - c0) * 256 + t];
      a0 += bf2f(v & 0xffffu);
      a1 += bf2f(v >> 16);
      const float inv = 1.0f / (float)(cntBase + r - beg + 1);
      const float g0 = fmaxf(fmaf(a0, inv, b0), 0.f);
      const float g1 = fmaxf(fmaf(a1, inv, b1v), 0.f);
      gp[(size_t)(r - c0) * 256 + t] = f2bf(g0) | (f2bf(g1) << 16);
    }
  }
  for (; base < end; base += P) {
#pragma unroll
    for (int p = 0; p < P; ++p) {
      const int r = base + p;
      if (r < end) {
        const uint32_t v = buf[p];
        buf[p] = (r + P < end) ? zp[(size_t)(r + P - c0) * 256 + t] : 0u;
        a0 += bf2f(v & 0xffffu);
        a1 += bf2f(v >> 16);
        const float inv = 1.0f / (float)(cntBase + r - beg + 1);
        const float g0 = fmaxf(fmaf(a0, inv, b0), 0.f);
        const float g1 = fmaxf(fmaf(a1, inv, b1v), 0.f);
        gp[(size_t)(r - c0) * 256 + t] = f2bf(g0) | (f2bf(g1) << 16);
      }
    }
  }

  carry_sum[s * 512 + 2 * t]     = a0;
  carry_sum[s * 512 + 2 * t + 1] = a1;
  if (t == 0) carry_cnt[s] = cntBase + (end - beg);
}

// ---------------- final: out[n,h] = X[n,:]@weff[0:128,h] + g[n,:]@weff[128:640,h] ----------------

__global__ __launch_bounds__(256)
void final_kernel(const float* __restrict__ X, const ushortT* __restrict__ g,
                  const float* __restrict__ weff, float* __restrict__ out, int rows) {
  const int t = (int)threadIdx.x;
  const int wv = t >> 6, lane = t & 63;

  float wx0[8], wx1[8], wg[8][8];
#pragma unroll
  for (int h = 0; h < 8; ++h) {
    wx0[h] = weff[(2 * lane) * 8 + h];
    wx1[h] = weff[(2 * lane + 1) * 8 + h];
  }
#pragma unroll
  for (int j = 0; j < 8; ++j)
#pragma unroll
    for (int h = 0; h < 8; ++h)
      wg[j][h] = weff[(128 + 8 * lane + j) * 8 + h];

  for (int row = (int)blockIdx.x * 4 + wv; row < rows; row += (int)gridDim.x * 4) {
    const float2 xv = *(const float2*)&X[(size_t)row * 128 + 2 * lane];
    const u16x8 gv = *(const u16x8*)&g[(size_t)row * 512 + 8 * lane];
    float pp[8];
#pragma unroll
    for (int h = 0; h < 8; ++h) pp[h] = xv.x * wx0[h] + xv.y * wx1[h];
#pragma unroll
    for (int j = 0; j < 8; ++j) {
      const float f = bf2f((uint32_t)gv[j]);
#pragma unroll
      for (int h = 0; h < 8; ++h) pp[h] = fmaf(f, wg[j][h], pp[h]);
    }
#pragma unroll
    for (int off = 32; off >= 1; off >>= 1) {
#pragma unroll
      for (int h = 0; h < 8; ++h) pp[h] += __shfl_xor(pp[h], off, 64);
    }
    if (lane == 0) {
#pragma unroll
      for (int h = 0; h < 8; ++h) out[(size_t)row * 8 + h] = pp[h];
    }
  }
}

// ---------------- launch ----------------

extern "C" void kernel_launch(void* const* d_in, const int* in_sizes, int n_in,
                              void* d_out, int out_size, void* d_ws, size_t ws_size,
                              hipStream_t stream) {
  const float* X  = (const float*)d_in[0];
  const int*   sg = (const int*)d_in[1];
  const float* W1 = (const float*)d_in[2];
  const float* b1 = (const float*)d_in[3];
  const float* W2 = (const float*)d_in[4];
  const float* b2 = (const float*)d_in[5];
  const float* W3 = (const float*)d_in[6];
  const float* b3 = (const float*)d_in[7];
  const float* Wr = (const float*)d_in[8];
  const float* br = (const float*)d_in[9];
  const float* Wk = (const float*)d_in[10];
  const float* Wq = (const float*)d_in[11];
  float* out = (float*)d_out;

  const size_t szW1T  = 512 * 128 * 2;
  const size_t szWT   = 512 * 512 * 2;
  const size_t szWeff = 640 * 8 * 4;
  const size_t szCSum = NSEG * 512 * 4;
  const size_t szCCnt = NSEG * 4;
  const size_t fixed  = szW1T + 3 * szWT + szWeff + szCSum + szCCnt;

  int CH = 0;
  const int cands[6] = {131072, 65536, 32768, 16384, 8192, 4096};
  for (int i = 0; i < 6; ++i) {
    const size_t need = fixed + (size_t)cands[i] * 128 * 2     // Xb chunk
                      + 2 * (size_t)cands[i] * 512 * 2;        // ping-pong
    if (need <= ws_size) { CH = cands[i]; break; }
  }
  if (CH == 0) CH = 4096;

  char* p = (char*)d_ws;
  ushortT* W1T  = (ushortT*)p; p += szW1T;
  ushortT* W2T  = (ushortT*)p; p += szWT;
  ushortT* W3T  = (ushortT*)p; p += szWT;
  ushortT* WrT  = (ushortT*)p; p += szWT;
  float*   weff = (float*)p;   p += szWeff;
  float*   cSum = (float*)p;   p += szCSum;
  int*     cCnt = (int*)p;     p += szCCnt;
  ushortT* Xb   = (ushortT*)p; p += (size_t)CH * 128 * 2;
  ushortT* p1   = (ushortT*)p; p += (size_t)CH * 512 * 2;
  ushortT* p2   = (ushortT*)p;

  transpose_bf16_kernel<<<(512 * 128 + 255) / 256, 256, 0, stream>>>(W1, W1T, 128, 512);
  transpose_bf16_kernel<<<(512 * 512 + 255) / 256, 256, 0, stream>>>(W2, W2T, 512, 512);
  transpose_bf16_kernel<<<(512 * 512 + 255) / 256, 256, 0, stream>>>(W3, W3T, 512, 512);
  transpose_bf16_kernel<<<(512 * 512 + 255) / 256, 256, 0, stream>>>(Wr, WrT, 512, 512);
  weff_kernel<<<640, 64, 0, stream>>>(Wk, Wq, weff);
  hipMemsetAsync(cSum, 0, szCSum + szCCnt, stream);

  for (int c0 = 0; c0 < N_TOK; c0 += CH) {
    const int gG = (CH / 256) * 4;
    const int gF = (CH / 4 < 4096) ? CH / 4 : 4096;
    convert_bf16_kernel<<<2048, 256, 0, stream>>>(X + (size_t)c0 * 128, Xb, CH * 128 / 4);
    gemm_ring_kernel<128, true,  true ><<<gG, 512, 0, stream>>>(Xb, W1T, b1, p1);
    gemm_ring_kernel<512, true,  true ><<<gG, 512, 0, stream>>>(p1, W2T, b2, p2);
    gemm_ring_kernel<512, true,  true ><<<gG, 512, 0, stream>>>(p2, W3T, b3, p1);
    gemm_ring_kernel<512, false, false><<<gG, 512, 0, stream>>>(p1, WrT, nullptr, p2);
    scan_kernel<<<NSEG, 256, 0, stream>>>(p2, p1, sg, br, cSum, cCnt, c0, CH);
    final_kernel<<<gF, 256, 0, stream>>>(X + (size_t)c0 * 128, p1, weff,
                                         out + (size_t)c0 * 8, CH);
  }
}